// Round 6
// baseline (69.631 us; speedup 1.0000x reference)
//
#include <hip/hip_runtime.h>

#define B_TOTAL 524288
#define TILE_B 128
#define TPB 8
#define GRID (B_TOTAL / (TILE_B * TPB))   // 512 blocks = 2/CU, fully resident
#define NTHR 512

// MSE weights after VAR_IDX mapping: ch0:0.15 ch1:0.15 ch2:0.5 ch3:0.1 ch4:0.1
// step_w = [0.48, 0.24, 0.16, 0.12]
// One thread per (b,s) within a tile; 8 tiles/block, double-buffered LDS,
// counted s_waitcnt vmcnt(8) so next tile's 8 VMEM ops stay in flight across
// the barrier (T3/T4 pattern). Never drain vmcnt to 0 in the main loop.

__device__ __forceinline__ void gload_lds16(const float4* g, float4* l) {
    __builtin_amdgcn_global_load_lds(
        (const __attribute__((address_space(1))) void*)g,
        (__attribute__((address_space(3))) void*)l, 16, 0, 0);
}

__global__ __launch_bounds__(NTHR) void loss_partial(
    const float* __restrict__ pred,    // (B,4,16)
    const float* __restrict__ target,  // (B,4,16)
    const float* __restrict__ inseq,   // (B,8,16)
    const float* __restrict__ scale,   // (16)
    const float* __restrict__ mean,    // (16)
    float* __restrict__ partials)      // (10, GRID)
{
    // Per buffer: sp 1536 f4 = 24KB (pred ch0-11), st 1024 f4 = 16KB (target ch0-7)
    // 2 buffers = 80KB total -> exactly 2 blocks/CU. Reduce scratch aliases st[0].
    __shared__ float4 sp[2][TILE_B * 12];
    __shared__ float4 st[2][TILE_B * 8];

    const int tid = threadIdx.x;
    const int b = tid >> 2;
    const int s = tid & 3;
    const int row = tid;               // b*4+s == tid
    const size_t blk0 = (size_t)blockIdx.x * (TPB * TILE_B);

    const float4* prg = reinterpret_cast<const float4*>(pred) + blk0 * 16;
    const float4* tgg = reinterpret_cast<const float4*>(target) + blk0 * 16;
    const float4* iqg = reinterpret_cast<const float4*>(inseq) + blk0 * 32 + (size_t)b * 32 + 28;

    // Precompute per-thread staging offsets (LDS slot j <- global element swz(j);
    // XOR swizzle is an involution, reads use the same swz).
    int po0, po1, po2, to0, to1;
    { int j = tid;        int i = j ^ ((j >> 3) & 7); int r = i / 3; po0 = r * 4 + (i - r * 3); }
    { int j = 512 + tid;  int i = j ^ ((j >> 3) & 7); int r = i / 3; po1 = r * 4 + (i - r * 3); }
    { int j = 1024 + tid; int i = j ^ ((j >> 3) & 7); int r = i / 3; po2 = r * 4 + (i - r * 3); }
    { int j = tid;        int i = j ^ ((j >> 3) & 7); to0 = ((i >> 1) << 2) | (i & 1); }
    { int j = 512 + tid;  int i = j ^ ((j >> 3) & 7); to1 = ((i >> 1) << 2) | (i & 1); }

    const float sc0 = scale[0], sc2 = scale[2], sc3 = scale[3], sc4 = scale[4];
    const float sc5 = scale[5], sc7 = scale[7], sc8 = scale[8], sc9 = scale[9], sc11 = scale[11];
    const float mn3 = mean[3], mn4 = mean[4];
    const float sw = (s == 0) ? 0.48f : (s == 1) ? 0.24f : (s == 2) ? 0.16f : 0.12f;

    // ---- staging: exactly 8 VMEM instrs per wave per tile (5 lds-DMA + 3 vec) ----
    auto STAGE = [&](int bi, int t) {
        const float4* pg = prg + (size_t)t * (TILE_B * 16);
        const float4* tg = tgg + (size_t)t * (TILE_B * 16);
        gload_lds16(pg + po0, &sp[bi][tid]);
        gload_lds16(pg + po1, &sp[bi][512 + tid]);
        gload_lds16(pg + po2, &sp[bi][1024 + tid]);
        gload_lds16(tg + to0, &st[bi][tid]);
        gload_lds16(tg + to1, &st[bi][512 + tid]);
    };
    auto LOADQ = [&](float4* q, int t) {
        if (s == 0) {   // every wave has 16 active lanes -> 3 VMEM issued per wave
            const float4* iq = iqg + (size_t)t * (TILE_B * 32);
            q[0] = iq[0]; q[1] = iq[1]; q[2] = iq[2];
        }
    };

    float acc_mse = 0.f, acc_rest = 0.f, hn = 0.f, hd = 0.f;

    auto COMPUTE = [&](int bi, const float4* q) {
        auto ldp = [&](int rr, int w) -> float4 {
            int i = rr * 3 + w; return sp[bi][i ^ ((i >> 3) & 7)];
        };
        auto ldt = [&](int rr, int h) -> float4 {
            int i = rr * 2 + h; return st[bi][i ^ ((i >> 3) & 7)];
        };
        float pv0, pv2, pv5, pv7, pv8, pv9, pv11;
        if (s != 0) {
            float4 a0 = ldp(row - 1, 0), a1 = ldp(row - 1, 1), a2 = ldp(row - 1, 2);
            pv0 = a0.x; pv2 = a0.z; pv5 = a1.y; pv7 = a1.w;
            pv8 = a2.x; pv9 = a2.y; pv11 = a2.w;
        } else {
            pv0 = q[0].x; pv2 = q[0].z; pv5 = q[1].y; pv7 = q[1].w;
            pv8 = q[2].x; pv9 = q[2].y; pv11 = q[2].w;
        }
        float4 p0 = ldp(row, 0), p1 = ldp(row, 1), p2 = ldp(row, 2);
        float4 t0 = ldt(row, 0), t1 = ldt(row, 1);

        // MSE ch0-4, step-weighted
        float d0 = p0.x - t0.x, d1 = p0.y - t0.y, d2 = p0.z - t0.z;
        float d3 = p0.w - t0.w, d4 = p1.x - t1.x;
        acc_mse += sw * (0.15f * d0 * d0 + 0.15f * d1 * d1 + 0.5f * d2 * d2 +
                         0.1f * d3 * d3 + 0.1f * d4 * d4);
        // heat balance (per-step sums; s fixed per thread)
        float air = p0.w * sc3 + mn3;
        float water = p1.x * sc4 + mn4;
        float hdf = air - water;
        hn += hdf * hdf;
        hd += air * air;
        // frost (ch2) / pressure (ch0): mean cancels in pd-pv
        float fr = fmaxf((pv2 - p0.z) * sc2, 0.f);
        float pg2 = fmaxf((pv0 - p0.x) * sc0, 0.f) * 0.5f;
        float rest = fr * fr + pg2 * pg2;
        // temp penalty ch 5,7,8,9,11
        float t5 = fmaxf(fabsf(p1.y - pv5) * sc5 - 5.f, 0.f);
        float t7 = fmaxf(fabsf(p1.w - pv7) * sc7 - 5.f, 0.f);
        float t8 = fmaxf(fabsf(p2.x - pv8) * sc8 - 5.f, 0.f);
        float t9 = fmaxf(fabsf(p2.y - pv9) * sc9 - 5.f, 0.f);
        float t11 = fmaxf(fabsf(p2.w - pv11) * sc11 - 5.f, 0.f);
        rest += 0.1f * (t5 * t5 + t7 * t7 + t8 * t8 + t9 * t9 + t11 * t11);
        acc_rest += sw * rest;
    };

    float4 qreg[2][3];

    // ---- pipelined main loop: prefetch t+1 before waiting on t ----
    STAGE(0, 0);
    LOADQ(qreg[0], 0);
#pragma unroll
    for (int t = 0; t < TPB; ++t) {
        const int cur = t & 1, nxt = (t + 1) & 1;
        if (t > 0) {
            // all waves done reading buf[nxt] (compute t-1) before DMA overwrites it
            asm volatile("s_barrier" ::: "memory");
        }
        if (t + 1 < TPB) {
            STAGE(nxt, t + 1);
            LOADQ(qreg[nxt], t + 1);
            asm volatile("s_waitcnt vmcnt(8)" ::: "memory");   // tile t landed; t+1 in flight
        } else {
            asm volatile("s_waitcnt vmcnt(0)" ::: "memory");   // last tile: drain
        }
        asm volatile("s_barrier" ::: "memory");                 // tile t visible to all waves
        COMPUTE(cur, qreg[cur]);
    }

    // ---- reductions (red aliases st[0]; safe: only buf1 in use at t=7) ----
    const int lane = tid & 63;
    const int wave = tid >> 6;
#pragma unroll
    for (int off = 1; off < 64; off <<= 1) {
        acc_mse  += __shfl_xor(acc_mse, off, 64);
        acc_rest += __shfl_xor(acc_rest, off, 64);
    }
#pragma unroll
    for (int off = 4; off < 64; off <<= 1) {
        hn += __shfl_xor(hn, off, 64);
        hd += __shfl_xor(hd, off, 64);
    }
    float* red = reinterpret_cast<float*>(&st[0][0]);
    if (lane == 0) { red[wave * 10 + 0] = acc_mse; red[wave * 10 + 1] = acc_rest; }
    if (lane < 4)  { red[wave * 10 + 2 + lane] = hn; red[wave * 10 + 6 + lane] = hd; }
    __syncthreads();

    if (tid < 10) {
        float v = 0.f;
#pragma unroll
        for (int w = 0; w < 8; ++w) v += red[w * 10 + tid];
        partials[tid * GRID + blockIdx.x] = v;
    }
}

__global__ __launch_bounds__(640) void loss_final(
    const float* __restrict__ partials,  // (10, GRID)
    float* __restrict__ out)
{
    __shared__ float tot[10];
    const int t = threadIdx.x;
    const int c = t >> 6;      // one wave per channel, 10 waves
    const int lane = t & 63;

    float v = 0.f;
#pragma unroll
    for (int i = 0; i < GRID / 64; ++i)
        v += partials[(size_t)c * GRID + i * 64 + lane];
#pragma unroll
    for (int off = 32; off; off >>= 1) v += __shfl_down(v, off, 64);
    if (lane == 0) tot[c] = v;
    __syncthreads();

    if (t == 0) {
        const float stepw[4] = {0.48f, 0.24f, 0.16f, 0.12f};
        const float invB = 1.0f / (float)B_TOTAL;
        float mse = tot[0] * invB;
        float phys = tot[1] * invB;
#pragma unroll
        for (int q = 0; q < 4; ++q) {
            float num = tot[2 + q] * invB;
            float den = tot[6 + q] * invB + 1e-6f;
            phys += stepw[q] * (num / den);
        }
        out[0] = mse + 0.1f * phys;
    }
}

extern "C" void kernel_launch(void* const* d_in, const int* in_sizes, int n_in,
                              void* d_out, int out_size, void* d_ws, size_t ws_size,
                              hipStream_t stream) {
    const float* pred   = (const float*)d_in[0];
    const float* target = (const float*)d_in[1];
    const float* inseq  = (const float*)d_in[2];
    const float* scale  = (const float*)d_in[3];
    const float* mean   = (const float*)d_in[4];
    float* out = (float*)d_out;
    float* partials = (float*)d_ws;  // 10 * GRID floats = 20 KB

    loss_partial<<<GRID, NTHR, 0, stream>>>(pred, target, inseq, scale, mean, partials);
    loss_final<<<1, 640, 0, stream>>>(partials, out);
}